// Round 8
// baseline (462.951 us; speedup 1.0000x reference)
//
#include <hip/hip_runtime.h>
#include <hip/hip_bf16.h>
#include <hip/hip_fp8.h>
#include <cstdint>
#include <cstddef>

typedef __bf16 bf16;
typedef bf16 bf16x4 __attribute__((ext_vector_type(4)));
typedef bf16 bf16x8 __attribute__((ext_vector_type(8)));
typedef float f32x4 __attribute__((ext_vector_type(4)));
typedef float f32x2 __attribute__((ext_vector_type(2)));

__device__ __forceinline__ float fp8_to_f32(uint8_t b) {
  __hip_fp8_e4m3 t; t.__x = (__hip_fp8_storage_t)b; return (float)t;
}
__device__ __forceinline__ uint8_t f32_to_fp8(float v) {
  __hip_fp8_e4m3 t(v); return (uint8_t)t.__x;
}

// ---------------- prep ----------------
__device__ __forceinline__ int kv_perm_to_orig(int nc) {
  int hh = nc >> 6, r6 = nc & 63, t = r6 >> 3, e = r6 & 7;
  int sel = e >> 2, cc = t * 4 + (e & 3);
  return hh * 64 + sel * 32 + cc;
}

__global__ __launch_bounds__(256) void prep_kernel(
    const float* __restrict__ q_w, const float* __restrict__ kv_w,
    const float* __restrict__ proj_w, const float* __restrict__ fc1_w,
    const float* __restrict__ fc2_w, const float* __restrict__ q_b,
    const float* __restrict__ kv_b,
    bf16* __restrict__ wqkv, bf16* __restrict__ wproj,
    bf16* __restrict__ wfc1, bf16* __restrict__ wfc2,
    float* __restrict__ qscale, float* __restrict__ qbias)
{
  int i = blockIdx.x * 256 + threadIdx.x;
  if (i < 196608) {
    int row = i >> 8, col = i & 255;
    float v;
    if (row < 256) v = q_w[i];
    else           v = kv_w[kv_perm_to_orig(row - 256) * 256 + col];
    wqkv[i] = (bf16)v;
  }
  if (i < 65536)  wproj[i] = (bf16)proj_w[i];
  if (i < 131072) { wfc1[i] = (bf16)fc1_w[i]; wfc2[i] = (bf16)fc2_w[i]; }
  if (i < 768) {
    const float s = 0.17677669529663687f;  // 1/sqrt(32)
    if (i < 256) { qscale[i] = s;    qbias[i] = q_b[i] * s; }
    else         { qscale[i] = 1.0f; qbias[i] = kv_b[kv_perm_to_orig(i - 256)]; }
  }
}

// ---------------- layernorm ----------------
__global__ __launch_bounds__(256) void ln_kernel(
    const float* __restrict__ in, const float* __restrict__ w,
    const float* __restrict__ b, bf16* __restrict__ out)
{
  const int wv = threadIdx.x >> 6, lane = threadIdx.x & 63;
  const int row = blockIdx.x * 4 + wv;
  f32x4 v = *((const f32x4*)(in + (size_t)row * 256) + lane);
  float s  = v[0] + v[1] + v[2] + v[3];
  float s2 = v[0]*v[0] + v[1]*v[1] + v[2]*v[2] + v[3]*v[3];
  #pragma unroll
  for (int o = 1; o < 64; o <<= 1) { s += __shfl_xor(s, o); s2 += __shfl_xor(s2, o); }
  float mu = s * (1.0f / 256.0f);
  float var = s2 * (1.0f / 256.0f) - mu * mu;
  float rstd = rsqrtf(var + 1e-5f);
  f32x4 wv4 = *((const f32x4*)w + lane);
  f32x4 bv4 = *((const f32x4*)b + lane);
  bf16x4 o4;
  o4[0] = (bf16)((v[0] - mu) * rstd * wv4[0] + bv4[0]);
  o4[1] = (bf16)((v[1] - mu) * rstd * wv4[1] + bv4[1]);
  o4[2] = (bf16)((v[2] - mu) * rstd * wv4[2] + bv4[2]);
  o4[3] = (bf16)((v[3] - mu) * rstd * wv4[3] + bv4[3]);
  *((bf16x4*)(out + (size_t)row * 256) + lane) = o4;
}

// ---------------- GEMM (unchanged from round 7) ----------------
template<int NF, int K>
__global__ __launch_bounds__(256) void gemm_bt(
    const bf16* __restrict__ A, const bf16* __restrict__ B,
    int N,
    const float* __restrict__ scale, const float* __restrict__ bias,
    const float* __restrict__ residual, int do_gelu,
    float* __restrict__ outf, bf16* __restrict__ outh,
    bf16* __restrict__ outq, uint8_t* __restrict__ outkv)
{
  constexpr int CN = NF * 16;
  constexpr int SPI = 64 / CN;
  __shared__ __align__(16) bf16 ldsB[K / 8][CN][8];
  const int tid = threadIdx.x;
  const int w = tid >> 6, lane = tid & 63;
  const int part = lane >> 4, r16 = lane & 15;
  const int rowBase = blockIdx.x * 64 + w * 16;
  const int colBase = blockIdx.y * CN;

  for (int s = w * SPI; s < K / 8; s += 4 * SPI) {
    const bf16* src = B + (size_t)(colBase + (lane & (CN - 1))) * K + (s + lane / CN) * 8;
    __builtin_amdgcn_global_load_lds(
        (const __attribute__((address_space(1))) uint32_t*)src,
        (__attribute__((address_space(3))) uint32_t*)&ldsB[s][0][0], 16, 0, 0);
  }

  f32x4 acc[NF] = {};
  const bf16* Aw = A + (size_t)(rowBase + r16) * K + part * 8;
  __syncthreads();

  #pragma unroll
  for (int p2 = 0; p2 < K / 32; ++p2) {
    bf16x8 af = *(const bf16x8*)(Aw + p2 * 32);
    bf16x8 bfr[NF];
    #pragma unroll
    for (int fn = 0; fn < NF; ++fn)
      bfr[fn] = *(const bf16x8*)&ldsB[p2 * 4 + part][fn * 16 + r16][0];
    #pragma unroll
    for (int fn = 0; fn < NF; ++fn)
      acc[fn] = __builtin_amdgcn_mfma_f32_16x16x32_bf16(af, bfr[fn], acc[fn], 0, 0, 0);
  }

  #pragma unroll
  for (int fn = 0; fn < NF; ++fn)
  #pragma unroll
  for (int r = 0; r < 4; ++r) {
    int row = rowBase + part * 4 + r;
    int col = colBase + fn * 16 + r16;
    float v = acc[fn][r];
    if (scale)    v *= scale[col];
    if (bias)     v += bias[col];
    if (do_gelu)  v = 0.5f * v * (1.0f + erff(v * 0.70710678118654752f));
    if (residual) v += residual[(size_t)row * N + col];
    if (outq) {
      if (col < 256) outq[(size_t)row * 256 + col] = (bf16)v;
      else           outkv[(size_t)row * 512 + (col - 256)] = f32_to_fp8(v);
    } else if (outf) {
      outf[(size_t)row * N + col] = v;
    } else {
      outh[(size_t)row * N + col] = (bf16)v;
    }
  }
}

// ---------------- real attention (unchanged from round 7) ----------------
__global__ __launch_bounds__(256) void attn_kernel(
    const bf16* __restrict__ qb,
    const uint8_t* __restrict__ kvf8,
    const int* __restrict__ member_idx,
    const int* __restrict__ pe_idx,
    const float* __restrict__ cluster_mask,
    const float* __restrict__ pre_table,
    const float* __restrict__ pe_w, const float* __restrict__ pe_b,
    const float* __restrict__ blank_k, const float* __restrict__ blank_v,
    bf16* __restrict__ out)
{
  __shared__ float posm[48][8];
  __shared__ float part_o[4][64][4];
  __shared__ float part_l[4][8];
  const int tid = threadIdx.x;
  const int w = tid >> 6, lane = tid & 63;
  const int bid = blockIdx.x;
  const int xcd = bid & 7, grp = bid >> 3;
  const int token = (xcd >> 2) * 4096 + (xcd & 3) * 1024 + grp;
  const int bb = token >> 12;
  const int hh = lane >> 3;
  const int j0 = w * 12;

  bf16x4 q4 = *((const bf16x4*)(qb + (size_t)token * 256) + lane);
  const float q0 = (float)q4[0], q1 = (float)q4[1], q2 = (float)q4[2], q3 = (float)q4[3];

  if (lane < 12) {
    int j = j0 + lane;
    int pj = __builtin_nontemporal_load(pe_idx + (size_t)token * 48 + j);
    const float* pt = pre_table + (size_t)pj * 5;
    float p0 = __builtin_nontemporal_load(pt + 0);
    float p1 = __builtin_nontemporal_load(pt + 1);
    float p2 = __builtin_nontemporal_load(pt + 2);
    float p3 = __builtin_nontemporal_load(pt + 3);
    float p4 = __builtin_nontemporal_load(pt + 4);
    float cm = __builtin_nontemporal_load(cluster_mask + (size_t)token * 48 + j);
    float mk = (1.0f - cm) * -100.0f;
    #pragma unroll
    for (int h = 0; h < 8; ++h) {
      posm[j][h] = p0 * pe_w[h*5+0] + p1 * pe_w[h*5+1] + p2 * pe_w[h*5+2]
                 + p3 * pe_w[h*5+3] + p4 * pe_w[h*5+4] + pe_b[h] + mk;
    }
  }
  int idx_lane = __builtin_nontemporal_load(
      member_idx + (size_t)token * 48 + j0 + (lane < 12 ? lane : 0));

  float l = 0.0f, o0 = 0.0f, o1 = 0.0f, o2 = 0.0f, o3 = 0.0f;
  if (w == 0) {
    f32x4 bk = *((const f32x4*)blank_k + lane);
    float db = q0 * bk[0] + q1 * bk[1] + q2 * bk[2] + q3 * bk[3];
    db += __shfl_xor(db, 1); db += __shfl_xor(db, 2); db += __shfl_xor(db, 4);
    float pb = __expf(db);
    l = pb;
    f32x4 bv = *((const f32x4*)blank_v + lane);
    o0 = pb * bv[0]; o1 = pb * bv[1]; o2 = pb * bv[2]; o3 = pb * bv[3];
  }
  __syncthreads();

  const uint8_t* kvbase = kvf8 + (size_t)(bb * 4096) * 512;
  #pragma unroll 6
  for (int jj = 0; jj < 12; ++jj) {
    int idx = __shfl(idx_lane, jj);
    uint64_t bits = *(const uint64_t*)(kvbase + (size_t)idx * 512 + lane * 8);
    float k0 = fp8_to_f32((uint8_t)(bits       ));
    float k1 = fp8_to_f32((uint8_t)(bits >>  8 ));
    float k2 = fp8_to_f32((uint8_t)(bits >> 16 ));
    float k3 = fp8_to_f32((uint8_t)(bits >> 24 ));
    float v0 = fp8_to_f32((uint8_t)(bits >> 32 ));
    float v1 = fp8_to_f32((uint8_t)(bits >> 40 ));
    float v2 = fp8_to_f32((uint8_t)(bits >> 48 ));
    float v3 = fp8_to_f32((uint8_t)(bits >> 56 ));
    float d = k0 * q0 + k1 * q1 + k2 * q2 + k3 * q3;
    d += __shfl_xor(d, 1); d += __shfl_xor(d, 2); d += __shfl_xor(d, 4);
    float p = __expf(d + posm[j0 + jj][hh]);
    l  += p;
    o0 += p * v0;
    o1 += p * v1;
    o2 += p * v2;
    o3 += p * v3;
  }
  part_o[w][lane][0] = o0; part_o[w][lane][1] = o1;
  part_o[w][lane][2] = o2; part_o[w][lane][3] = o3;
  if ((lane & 7) == 0) part_l[w][hh] = l;
  __syncthreads();

  if (w == 0) {
    float L  = part_l[0][hh] + part_l[1][hh] + part_l[2][hh] + part_l[3][hh];
    float O0 = part_o[0][lane][0] + part_o[1][lane][0] + part_o[2][lane][0] + part_o[3][lane][0];
    float O1 = part_o[0][lane][1] + part_o[1][lane][1] + part_o[2][lane][1] + part_o[3][lane][1];
    float O2 = part_o[0][lane][2] + part_o[1][lane][2] + part_o[2][lane][2] + part_o[3][lane][2];
    float O3 = part_o[0][lane][3] + part_o[1][lane][3] + part_o[2][lane][3] + part_o[3][lane][3];
    float inv = 1.0f / L;
    bf16x4 ov;
    ov[0] = (bf16)(O0 * inv); ov[1] = (bf16)(O1 * inv);
    ov[2] = (bf16)(O2 * inv); ov[3] = (bf16)(O3 * inv);
    *((bf16x4*)(out + (size_t)token * 256) + lane) = ov;
  }
}

// ---------------- DIAGNOSTIC PROBES: ablation variants, write to scratch ----------------
// MODE 0: full (doubled: 2 tokens/block). 1: no pe/pre_table/mask loads. 2: sequential
// KV idx (no gather randomness). 3: native fp8 converts. 4: 1+2+3 combined floor.
template<int MODE>
__global__ __launch_bounds__(256) void attn_probe(
    const bf16* __restrict__ qb,
    const uint8_t* __restrict__ kvf8,
    const int* __restrict__ member_idx,
    const int* __restrict__ pe_idx,
    const float* __restrict__ cluster_mask,
    const float* __restrict__ pre_table,
    const float* __restrict__ pe_w, const float* __restrict__ pe_b,
    const float* __restrict__ blank_k, const float* __restrict__ blank_v,
    bf16* __restrict__ scratch)
{
  constexpr bool NOPOSM = (MODE == 1 || MODE == 4);
  constexpr bool SEQG   = (MODE == 2 || MODE == 4);
  constexpr bool NATIVE = (MODE == 3 || MODE == 4);
  __shared__ float posm[48][8];
  __shared__ float part_o[4][64][4];
  __shared__ float part_l[4][8];
  const int tid = threadIdx.x;
  const int w = tid >> 6, lane = tid & 63;
  const int bid = blockIdx.x;
  const int xcd = bid & 7, grp = bid >> 3;
  const int token0 = (xcd >> 2) * 4096 + (xcd & 3) * 1024 + grp;
  const int hh = lane >> 3;
  const int j0 = w * 12;

  for (int rep = 0; rep < 2; ++rep) {
    const int token = token0 ^ (rep << 11);   // second token 2048 away, same batch half
    const int bb = token >> 12;
    bf16x4 q4 = *((const bf16x4*)(qb + (size_t)token * 256) + lane);
    const float q0 = (float)q4[0], q1 = (float)q4[1], q2 = (float)q4[2], q3 = (float)q4[3];

    if (lane < 12) {
      int j = j0 + lane;
      float p0, p1, p2, p3, p4, mk;
      if constexpr (!NOPOSM) {
        int pj = __builtin_nontemporal_load(pe_idx + (size_t)token * 48 + j);
        const float* pt = pre_table + (size_t)pj * 5;
        p0 = __builtin_nontemporal_load(pt + 0);
        p1 = __builtin_nontemporal_load(pt + 1);
        p2 = __builtin_nontemporal_load(pt + 2);
        p3 = __builtin_nontemporal_load(pt + 3);
        p4 = __builtin_nontemporal_load(pt + 4);
        float cm = __builtin_nontemporal_load(cluster_mask + (size_t)token * 48 + j);
        mk = (1.0f - cm) * -100.0f;
      } else {
        p0 = (float)lane * 0.01f; p1 = (float)j * 0.001f; p2 = 0.1f; p3 = 0.2f; p4 = 0.3f;
        mk = 0.0f;
      }
      #pragma unroll
      for (int h = 0; h < 8; ++h) {
        posm[j][h] = p0 * pe_w[h*5+0] + p1 * pe_w[h*5+1] + p2 * pe_w[h*5+2]
                   + p3 * pe_w[h*5+3] + p4 * pe_w[h*5+4] + pe_b[h] + mk;
      }
    }
    int idx_lane;
    if constexpr (SEQG)
      idx_lane = (grp * 48 + j0 + (lane < 12 ? lane : 0)) & 4095;
    else
      idx_lane = __builtin_nontemporal_load(
          member_idx + (size_t)token * 48 + j0 + (lane < 12 ? lane : 0));

    float l = 0.0f, o0 = 0.0f, o1 = 0.0f, o2 = 0.0f, o3 = 0.0f;
    if (w == 0) {
      f32x4 bk = *((const f32x4*)blank_k + lane);
      float db = q0 * bk[0] + q1 * bk[1] + q2 * bk[2] + q3 * bk[3];
      db += __shfl_xor(db, 1); db += __shfl_xor(db, 2); db += __shfl_xor(db, 4);
      float pb = __expf(db);
      l = pb;
      f32x4 bv = *((const f32x4*)blank_v + lane);
      o0 = pb * bv[0]; o1 = pb * bv[1]; o2 = pb * bv[2]; o3 = pb * bv[3];
    }
    __syncthreads();

    const uint8_t* kvbase = kvf8 + (size_t)(bb * 4096) * 512;
    #pragma unroll 6
    for (int jj = 0; jj < 12; ++jj) {
      int idx = __shfl(idx_lane, jj);
      float k0, k1, k2, k3, v0, v1, v2, v3;
      if constexpr (NATIVE) {
#if __has_builtin(__builtin_amdgcn_cvt_pk_f32_fp8)
        int2 ii = *(const int2*)(kvbase + (size_t)idx * 512 + lane * 8);
        f32x2 a = __builtin_amdgcn_cvt_pk_f32_fp8(ii.x, false);
        f32x2 b = __builtin_amdgcn_cvt_pk_f32_fp8(ii.x, true);
        f32x2 c = __builtin_amdgcn_cvt_pk_f32_fp8(ii.y, false);
        f32x2 e = __builtin_amdgcn_cvt_pk_f32_fp8(ii.y, true);
        k0 = a[0]; k1 = a[1]; k2 = b[0]; k3 = b[1];
        v0 = c[0]; v1 = c[1]; v2 = e[0]; v3 = e[1];
#else
        uint64_t bits = *(const uint64_t*)(kvbase + (size_t)idx * 512 + lane * 8);
        k0 = fp8_to_f32((uint8_t)bits);         k1 = fp8_to_f32((uint8_t)(bits >> 8));
        k2 = fp8_to_f32((uint8_t)(bits >> 16)); k3 = fp8_to_f32((uint8_t)(bits >> 24));
        v0 = fp8_to_f32((uint8_t)(bits >> 32)); v1 = fp8_to_f32((uint8_t)(bits >> 40));
        v2 = fp8_to_f32((uint8_t)(bits >> 48)); v3 = fp8_to_f32((uint8_t)(bits >> 56));
#endif
      } else {
        uint64_t bits = *(const uint64_t*)(kvbase + (size_t)idx * 512 + lane * 8);
        k0 = fp8_to_f32((uint8_t)bits);         k1 = fp8_to_f32((uint8_t)(bits >> 8));
        k2 = fp8_to_f32((uint8_t)(bits >> 16)); k3 = fp8_to_f32((uint8_t)(bits >> 24));
        v0 = fp8_to_f32((uint8_t)(bits >> 32)); v1 = fp8_to_f32((uint8_t)(bits >> 40));
        v2 = fp8_to_f32((uint8_t)(bits >> 48)); v3 = fp8_to_f32((uint8_t)(bits >> 56));
      }
      float d = k0 * q0 + k1 * q1 + k2 * q2 + k3 * q3;
      d += __shfl_xor(d, 1); d += __shfl_xor(d, 2); d += __shfl_xor(d, 4);
      float p = __expf(d + posm[j0 + jj][hh]);
      l  += p;
      o0 += p * v0; o1 += p * v1; o2 += p * v2; o3 += p * v3;
    }
    part_o[w][lane][0] = o0; part_o[w][lane][1] = o1;
    part_o[w][lane][2] = o2; part_o[w][lane][3] = o3;
    if ((lane & 7) == 0) part_l[w][hh] = l;
    __syncthreads();

    if (w == 0) {
      float L  = part_l[0][hh] + part_l[1][hh] + part_l[2][hh] + part_l[3][hh];
      float O0 = part_o[0][lane][0] + part_o[1][lane][0] + part_o[2][lane][0] + part_o[3][lane][0];
      float O1 = part_o[0][lane][1] + part_o[1][lane][1] + part_o[2][lane][1] + part_o[3][lane][1];
      float O2 = part_o[0][lane][2] + part_o[1][lane][2] + part_o[2][lane][2] + part_o[3][lane][2];
      float O3 = part_o[0][lane][3] + part_o[1][lane][3] + part_o[2][lane][3] + part_o[3][lane][3];
      float inv = 1.0f / L;
      bf16x4 ov;
      ov[0] = (bf16)(O0 * inv); ov[1] = (bf16)(O1 * inv);
      ov[2] = (bf16)(O2 * inv); ov[3] = (bf16)(O3 * inv);
      *((bf16x4*)(scratch + (size_t)token * 256) + lane) = ov;
    }
    __syncthreads();   // protect LDS reuse across reps
  }
}

// ---------------- host launcher ----------------
extern "C" void kernel_launch(void* const* d_in, const int* in_sizes, int n_in,
                              void* d_out, int out_size, void* d_ws, size_t ws_size,
                              hipStream_t stream)
{
  (void)in_sizes; (void)n_in; (void)out_size; (void)ws_size;
  const float* feat         = (const float*)d_in[0];
  const float* cluster_mask = (const float*)d_in[1];
  const float* pre_table    = (const float*)d_in[2];
  const float* norm1_w      = (const float*)d_in[3];
  const float* norm1_b      = (const float*)d_in[4];
  const float* q_w    = (const float*)d_in[5];
  const float* q_b    = (const float*)d_in[6];
  const float* kv_w   = (const float*)d_in[7];
  const float* kv_b   = (const float*)d_in[8];
  const float* blank_k = (const float*)d_in[9];
  const float* blank_v = (const float*)d_in[10];
  const float* pe_w   = (const float*)d_in[11];
  const float* pe_b   = (const float*)d_in[12];
  const float* proj_w = (const float*)d_in[13];
  const float* proj_b = (const float*)d_in[14];
  const float* norm2_w = (const float*)d_in[15];
  const float* norm2_b = (const float*)d_in[16];
  const float* fc1_w  = (const float*)d_in[17];
  const float* fc1_b  = (const float*)d_in[18];
  const float* fc2_w  = (const float*)d_in[19];
  const float* fc2_b  = (const float*)d_in[20];
  const int* member_idx = (const int*)d_in[21];
  const int* pe_idx     = (const int*)d_in[22];

  char* ws = (char*)d_ws;
  size_t off = 0;
  auto alloc = [&](size_t bytes) -> void* {
    void* p = ws + off; off += (bytes + 255) & ~(size_t)255; return p;
  };
  bf16*  wqkv  = (bf16*)alloc(768 * 256 * sizeof(bf16));
  bf16*  wproj = (bf16*)alloc(256 * 256 * sizeof(bf16));
  bf16*  wfc1  = (bf16*)alloc(512 * 256 * sizeof(bf16));
  bf16*  wfc2  = (bf16*)alloc(256 * 512 * sizeof(bf16));
  float* qscale = (float*)alloc(768 * sizeof(float));
  float* qbias  = (float*)alloc(768 * sizeof(float));
  bf16*    xbuf = (bf16*)alloc((size_t)8192 * 256 * sizeof(bf16));
  bf16*    qb   = (bf16*)alloc((size_t)8192 * 256 * sizeof(bf16));
  uint8_t* kvf8 = (uint8_t*)alloc((size_t)8192 * 512);
  bf16*    y1   = (bf16*)alloc((size_t)8192 * 512 * sizeof(bf16));
  bf16*  attnb = (bf16*)alloc((size_t)8192 * 256 * sizeof(bf16));
  float* feat2 = (float*)alloc((size_t)8192 * 256 * sizeof(float));
  float* outf = (float*)d_out;
  bf16* scratch = (bf16*)feat2;   // probe sink; fully overwritten by proj GEMM later

  // ---- diagnostic probes (timing-only; results discarded) ----
  attn_probe<0><<<dim3(8192), dim3(256), 0, stream>>>(qb, kvf8, member_idx, pe_idx,
      cluster_mask, pre_table, pe_w, pe_b, blank_k, blank_v, scratch);
  attn_probe<1><<<dim3(8192), dim3(256), 0, stream>>>(qb, kvf8, member_idx, pe_idx,
      cluster_mask, pre_table, pe_w, pe_b, blank_k, blank_v, scratch);
  attn_probe<2><<<dim3(8192), dim3(256), 0, stream>>>(qb, kvf8, member_idx, pe_idx,
      cluster_mask, pre_table, pe_w, pe_b, blank_k, blank_v, scratch);
  attn_probe<3><<<dim3(8192), dim3(256), 0, stream>>>(qb, kvf8, member_idx, pe_idx,
      cluster_mask, pre_table, pe_w, pe_b, blank_k, blank_v, scratch);
  attn_probe<4><<<dim3(8192), dim3(256), 0, stream>>>(qb, kvf8, member_idx, pe_idx,
      cluster_mask, pre_table, pe_w, pe_b, blank_k, blank_v, scratch);

  // ---- real pipeline (identical to round 7) ----
  prep_kernel<<<dim3(768), dim3(256), 0, stream>>>(
      q_w, kv_w, proj_w, fc1_w, fc2_w, q_b, kv_b,
      wqkv, wproj, wfc1, wfc2, qscale, qbias);
  ln_kernel<<<dim3(2048), dim3(256), 0, stream>>>(feat, norm1_w, norm1_b, xbuf);
  gemm_bt<4, 256><<<dim3(128, 12), dim3(256), 0, stream>>>(
      xbuf, wqkv, 768, qscale, qbias, (const float*)nullptr, 0,
      (float*)nullptr, (bf16*)nullptr, qb, kvf8);
  attn_kernel<<<dim3(8192), dim3(256), 0, stream>>>(
      qb, kvf8, member_idx, pe_idx, cluster_mask, pre_table,
      pe_w, pe_b, blank_k, blank_v, attnb);
  gemm_bt<2, 256><<<dim3(128, 8), dim3(256), 0, stream>>>(
      attnb, wproj, 256, (const float*)nullptr, proj_b,
      feat, 0, feat2, (bf16*)nullptr, (bf16*)nullptr, (uint8_t*)nullptr);
  ln_kernel<<<dim3(2048), dim3(256), 0, stream>>>(feat2, norm2_w, norm2_b, xbuf);
  gemm_bt<4, 256><<<dim3(128, 8), dim3(256), 0, stream>>>(
      xbuf, wfc1, 512, (const float*)nullptr, fc1_b,
      (const float*)nullptr, 1, (float*)nullptr, y1, (bf16*)nullptr, (uint8_t*)nullptr);
  gemm_bt<2, 512><<<dim3(128, 8), dim3(256), 0, stream>>>(
      y1, wfc2, 256, (const float*)nullptr, fc2_b,
      feat2, 0, outf, (bf16*)nullptr, (bf16*)nullptr, (uint8_t*)nullptr);
}

// Round 9
// 123.796 us; speedup vs baseline: 3.7396x; 3.7396x over previous
//
#include <hip/hip_runtime.h>
#include <hip/hip_bf16.h>
#include <hip/hip_fp8.h>
#include <cstdint>
#include <cstddef>

typedef __bf16 bf16;
typedef bf16 bf16x4 __attribute__((ext_vector_type(4)));
typedef bf16 bf16x8 __attribute__((ext_vector_type(8)));
typedef float f32x4 __attribute__((ext_vector_type(4)));
typedef float f32x2 __attribute__((ext_vector_type(2)));

__device__ __forceinline__ float fp8_to_f32(uint8_t b) {
  __hip_fp8_e4m3 t; t.__x = (__hip_fp8_storage_t)b; return (float)t;
}
__device__ __forceinline__ uint8_t f32_to_fp8(float v) {
  __hip_fp8_e4m3 t(v); return (uint8_t)t.__x;
}

// convert 4 fp8 (one dword, little-endian byte order) -> 4 f32
__device__ __forceinline__ void cvt4_fp8(int w, float* f) {
#if __has_builtin(__builtin_amdgcn_cvt_pk_f32_fp8)
  f32x2 a = __builtin_amdgcn_cvt_pk_f32_fp8(w, false);
  f32x2 b = __builtin_amdgcn_cvt_pk_f32_fp8(w, true);
  f[0] = a[0]; f[1] = a[1]; f[2] = b[0]; f[3] = b[1];
#else
  f[0] = fp8_to_f32((uint8_t)w);
  f[1] = fp8_to_f32((uint8_t)(w >> 8));
  f[2] = fp8_to_f32((uint8_t)(w >> 16));
  f[3] = fp8_to_f32((uint8_t)(w >> 24));
#endif
}

// ---------------- prep: weights -> bf16; kv rows permuted to [k(256)|v(256)] ----------------
// qkv activation col 256+j: j<256 -> k[h=j>>5][c=j&31] (orig row h*64+c),
//                           j>=256 -> v[h][c] (orig row h*64+32+c).
__device__ __forceinline__ int kv_perm_to_orig(int j) {
  int jj = j & 255, h = jj >> 5, c = jj & 31;
  return h * 64 + ((j >> 8) ? 32 : 0) + c;
}

__global__ __launch_bounds__(256) void prep_kernel(
    const float* __restrict__ q_w, const float* __restrict__ kv_w,
    const float* __restrict__ proj_w, const float* __restrict__ fc1_w,
    const float* __restrict__ fc2_w, const float* __restrict__ q_b,
    const float* __restrict__ kv_b,
    bf16* __restrict__ wqkv, bf16* __restrict__ wproj,
    bf16* __restrict__ wfc1, bf16* __restrict__ wfc2,
    float* __restrict__ qscale, float* __restrict__ qbias)
{
  int i = blockIdx.x * 256 + threadIdx.x;
  if (i < 196608) {
    int row = i >> 8, col = i & 255;
    float v;
    if (row < 256) v = q_w[i];
    else           v = kv_w[kv_perm_to_orig(row - 256) * 256 + col];
    wqkv[i] = (bf16)v;
  }
  if (i < 65536)  wproj[i] = (bf16)proj_w[i];
  if (i < 131072) { wfc1[i] = (bf16)fc1_w[i]; wfc2[i] = (bf16)fc2_w[i]; }
  if (i < 768) {
    const float s = 0.17677669529663687f;  // 1/sqrt(32)
    if (i < 256) { qscale[i] = s;    qbias[i] = q_b[i] * s; }
    else         { qscale[i] = 1.0f; qbias[i] = kv_b[kv_perm_to_orig(i - 256)]; }
  }
}

// ---------------- layernorm ----------------
__global__ __launch_bounds__(256) void ln_kernel(
    const float* __restrict__ in, const float* __restrict__ w,
    const float* __restrict__ b, bf16* __restrict__ out)
{
  const int wv = threadIdx.x >> 6, lane = threadIdx.x & 63;
  const int row = blockIdx.x * 4 + wv;
  f32x4 v = *((const f32x4*)(in + (size_t)row * 256) + lane);
  float s  = v[0] + v[1] + v[2] + v[3];
  float s2 = v[0]*v[0] + v[1]*v[1] + v[2]*v[2] + v[3]*v[3];
  #pragma unroll
  for (int o = 1; o < 64; o <<= 1) { s += __shfl_xor(s, o); s2 += __shfl_xor(s2, o); }
  float mu = s * (1.0f / 256.0f);
  float var = s2 * (1.0f / 256.0f) - mu * mu;
  float rstd = rsqrtf(var + 1e-5f);
  f32x4 wv4 = *((const f32x4*)w + lane);
  f32x4 bv4 = *((const f32x4*)b + lane);
  bf16x4 o4;
  o4[0] = (bf16)((v[0] - mu) * rstd * wv4[0] + bv4[0]);
  o4[1] = (bf16)((v[1] - mu) * rstd * wv4[1] + bv4[1]);
  o4[2] = (bf16)((v[2] - mu) * rstd * wv4[2] + bv4[2]);
  o4[3] = (bf16)((v[3] - mu) * rstd * wv4[3] + bv4[3]);
  *((bf16x4*)(out + (size_t)row * 256) + lane) = o4;
}

// ---------------- GEMM (unchanged structure) ----------------
template<int NF, int K>
__global__ __launch_bounds__(256) void gemm_bt(
    const bf16* __restrict__ A, const bf16* __restrict__ B,
    int N,
    const float* __restrict__ scale, const float* __restrict__ bias,
    const float* __restrict__ residual, int do_gelu,
    float* __restrict__ outf, bf16* __restrict__ outh,
    bf16* __restrict__ outq, uint8_t* __restrict__ outkv)
{
  constexpr int CN = NF * 16;
  constexpr int SPI = 64 / CN;
  __shared__ __align__(16) bf16 ldsB[K / 8][CN][8];
  const int tid = threadIdx.x;
  const int w = tid >> 6, lane = tid & 63;
  const int part = lane >> 4, r16 = lane & 15;
  const int rowBase = blockIdx.x * 64 + w * 16;
  const int colBase = blockIdx.y * CN;

  for (int s = w * SPI; s < K / 8; s += 4 * SPI) {
    const bf16* src = B + (size_t)(colBase + (lane & (CN - 1))) * K + (s + lane / CN) * 8;
    __builtin_amdgcn_global_load_lds(
        (const __attribute__((address_space(1))) uint32_t*)src,
        (__attribute__((address_space(3))) uint32_t*)&ldsB[s][0][0], 16, 0, 0);
  }

  f32x4 acc[NF] = {};
  const bf16* Aw = A + (size_t)(rowBase + r16) * K + part * 8;
  __syncthreads();

  #pragma unroll
  for (int p2 = 0; p2 < K / 32; ++p2) {
    bf16x8 af = *(const bf16x8*)(Aw + p2 * 32);
    bf16x8 bfr[NF];
    #pragma unroll
    for (int fn = 0; fn < NF; ++fn)
      bfr[fn] = *(const bf16x8*)&ldsB[p2 * 4 + part][fn * 16 + r16][0];
    #pragma unroll
    for (int fn = 0; fn < NF; ++fn)
      acc[fn] = __builtin_amdgcn_mfma_f32_16x16x32_bf16(af, bfr[fn], acc[fn], 0, 0, 0);
  }

  #pragma unroll
  for (int fn = 0; fn < NF; ++fn)
  #pragma unroll
  for (int r = 0; r < 4; ++r) {
    int row = rowBase + part * 4 + r;
    int col = colBase + fn * 16 + r16;
    float v = acc[fn][r];
    if (scale)    v *= scale[col];
    if (bias)     v += bias[col];
    if (do_gelu)  v = 0.5f * v * (1.0f + erff(v * 0.70710678118654752f));
    if (residual) v += residual[(size_t)row * N + col];
    if (outq) {
      if (col < 256) outq[(size_t)row * 256 + col] = (bf16)v;
      else           outkv[(size_t)row * 512 + (col - 256)] = f32_to_fp8(v);
    } else if (outf) {
      outf[(size_t)row * N + col] = v;
    } else {
      outh[(size_t)row * N + col] = (bf16)v;
    }
  }
}

// ---------------- posm: decoupled pe_table gather, thread per (token, j) ----------------
__global__ __launch_bounds__(256) void posm_kernel(
    const int* __restrict__ pe_idx,
    const float* __restrict__ cluster_mask,
    const float* __restrict__ pre_table,
    const float* __restrict__ pe_w, const float* __restrict__ pe_b,
    float* __restrict__ posm)   // [8192*48][8]
{
  int i = blockIdx.x * 256 + threadIdx.x;   // (token, j) flat, < 393216
  int pj = pe_idx[i];
  const float* pt = pre_table + (size_t)pj * 5;
  float p0 = pt[0], p1 = pt[1], p2 = pt[2], p3 = pt[3], p4 = pt[4];
  float mk = (1.0f - cluster_mask[i]) * -100.0f;
  f32x4 lo, hi;
  #pragma unroll
  for (int h = 0; h < 8; ++h) {
    float v = p0 * pe_w[h*5+0] + p1 * pe_w[h*5+1] + p2 * pe_w[h*5+2]
            + p3 * pe_w[h*5+3] + p4 * pe_w[h*5+4] + pe_b[h] + mk;
    if (h < 4) lo[h] = v; else hi[h-4] = v;
  }
  *((f32x4*)(posm + (size_t)i * 8))     = lo;
  *((f32x4*)(posm + (size_t)i * 8 + 4)) = hi;
}

// ---------------- attention v2: wave per token, lane = (neighbor n, head h) ----------------
// Lane-local 32-wide dot (no per-iteration shuffles), 1 exp per (n,h), native fp8 cvt,
// pos precomputed and read coalesced. No LDS, no barriers. 6 iterations of 8 neighbors.
__global__ __launch_bounds__(256) void attn_kernel(
    const bf16* __restrict__ qb,
    const uint8_t* __restrict__ kvf8,
    const int* __restrict__ member_idx,
    const float* __restrict__ posm,
    const float* __restrict__ blank_k, const float* __restrict__ blank_v,
    bf16* __restrict__ out)
{
  const int wv = threadIdx.x >> 6, lane = threadIdx.x & 63;
  const int token = blockIdx.x * 4 + wv;
  const int bb = token >> 12;
  const int n = lane >> 3, h = lane & 7;

  // q[32] for head h (f32)
  float q[32];
  {
    const bf16* qrow = qb + (size_t)token * 256 + h * 32;
    #pragma unroll
    for (int c8 = 0; c8 < 4; ++c8) {
      bf16x8 t = *(const bf16x8*)(qrow + c8 * 8);
      #pragma unroll
      for (int e = 0; e < 8; ++e) q[c8 * 8 + e] = (float)t[e];
    }
  }

  // preload member indices and pos terms (coalesced)
  int   midx[6];
  float pos[6];
  #pragma unroll
  for (int m = 0; m < 6; ++m) {
    midx[m] = member_idx[(size_t)token * 48 + m * 8 + n];
    pos[m]  = posm[(size_t)token * 384 + m * 64 + lane];
  }

  // blank token: group n==0 seeds the accumulator
  float l = 0.0f, o[32] = {};
  {
    float db = 0.0f;
    #pragma unroll
    for (int c4 = 0; c4 < 8; ++c4) {
      f32x4 bk = *((const f32x4*)(blank_k + h * 32) + c4);
      db += q[c4*4+0]*bk[0] + q[c4*4+1]*bk[1] + q[c4*4+2]*bk[2] + q[c4*4+3]*bk[3];
    }
    float pb = __expf(db);
    if (n == 0) {
      l = pb;
      #pragma unroll
      for (int c4 = 0; c4 < 8; ++c4) {
        f32x4 bv = *((const f32x4*)(blank_v + h * 32) + c4);
        o[c4*4+0] = pb*bv[0]; o[c4*4+1] = pb*bv[1];
        o[c4*4+2] = pb*bv[2]; o[c4*4+3] = pb*bv[3];
      }
    }
  }

  const uint8_t* kvb = kvf8 + (size_t)(bb * 4096) * 512;
  #pragma unroll
  for (int m = 0; m < 6; ++m) {
    const uint8_t* kp = kvb + (size_t)midx[m] * 512 + h * 32;
    int4 kw = *(const int4*)kp;          // k[0..15]
    int4 kx = *(const int4*)(kp + 16);   // k[16..31]
    int4 vw = *(const int4*)(kp + 256);  // v[0..15]
    int4 vx = *(const int4*)(kp + 272);  // v[16..31]

    float kf[8];
    float d = 0.0f;
    cvt4_fp8(kw.x, kf); cvt4_fp8(kw.y, kf + 4);
    #pragma unroll
    for (int c = 0; c < 8; ++c) d += q[c] * kf[c];
    cvt4_fp8(kw.z, kf); cvt4_fp8(kw.w, kf + 4);
    #pragma unroll
    for (int c = 0; c < 8; ++c) d += q[8 + c] * kf[c];
    cvt4_fp8(kx.x, kf); cvt4_fp8(kx.y, kf + 4);
    #pragma unroll
    for (int c = 0; c < 8; ++c) d += q[16 + c] * kf[c];
    cvt4_fp8(kx.z, kf); cvt4_fp8(kx.w, kf + 4);
    #pragma unroll
    for (int c = 0; c < 8; ++c) d += q[24 + c] * kf[c];

    float p = __expf(d + pos[m]);
    l += p;

    float vf[8];
    cvt4_fp8(vw.x, vf); cvt4_fp8(vw.y, vf + 4);
    #pragma unroll
    for (int c = 0; c < 8; ++c) o[c] += p * vf[c];
    cvt4_fp8(vw.z, vf); cvt4_fp8(vw.w, vf + 4);
    #pragma unroll
    for (int c = 0; c < 8; ++c) o[8 + c] += p * vf[c];
    cvt4_fp8(vx.x, vf); cvt4_fp8(vx.y, vf + 4);
    #pragma unroll
    for (int c = 0; c < 8; ++c) o[16 + c] += p * vf[c];
    cvt4_fp8(vx.z, vf); cvt4_fp8(vx.w, vf + 4);
    #pragma unroll
    for (int c = 0; c < 8; ++c) o[24 + c] += p * vf[c];
  }

  // reduce across the 8 neighbor-groups (lanes with same h)
  #pragma unroll
  for (int off = 8; off < 64; off <<= 1) {
    l += __shfl_xor(l, off);
    #pragma unroll
    for (int c = 0; c < 32; ++c) o[c] += __shfl_xor(o[c], off);
  }

  if (n == 0) {
    float inv = 1.0f / l;
    bf16* orow = out + (size_t)token * 256 + h * 32;
    #pragma unroll
    for (int c8 = 0; c8 < 4; ++c8) {
      bf16x8 t;
      #pragma unroll
      for (int e = 0; e < 8; ++e) t[e] = (bf16)(o[c8 * 8 + e] * inv);
      *(bf16x8*)(orow + c8 * 8) = t;
    }
  }
}

// ---------------- host launcher ----------------
extern "C" void kernel_launch(void* const* d_in, const int* in_sizes, int n_in,
                              void* d_out, int out_size, void* d_ws, size_t ws_size,
                              hipStream_t stream)
{
  (void)in_sizes; (void)n_in; (void)out_size; (void)ws_size;
  const float* feat         = (const float*)d_in[0];
  const float* cluster_mask = (const float*)d_in[1];
  const float* pre_table    = (const float*)d_in[2];
  const float* norm1_w      = (const float*)d_in[3];
  const float* norm1_b      = (const float*)d_in[4];
  const float* q_w    = (const float*)d_in[5];
  const float* q_b    = (const float*)d_in[6];
  const float* kv_w   = (const float*)d_in[7];
  const float* kv_b   = (const float*)d_in[8];
  const float* blank_k = (const float*)d_in[9];
  const float* blank_v = (const float*)d_in[10];
  const float* pe_w   = (const float*)d_in[11];
  const float* pe_b   = (const float*)d_in[12];
  const float* proj_w = (const float*)d_in[13];
  const float* proj_b = (const float*)d_in[14];
  const float* norm2_w = (const float*)d_in[15];
  const float* norm2_b = (const float*)d_in[16];
  const float* fc1_w  = (const float*)d_in[17];
  const float* fc1_b  = (const float*)d_in[18];
  const float* fc2_w  = (const float*)d_in[19];
  const float* fc2_b  = (const float*)d_in[20];
  const int* member_idx = (const int*)d_in[21];
  const int* pe_idx     = (const int*)d_in[22];

  char* ws = (char*)d_ws;
  size_t off = 0;
  auto alloc = [&](size_t bytes) -> void* {
    void* p = ws + off; off += (bytes + 255) & ~(size_t)255; return p;
  };
  bf16*  wqkv  = (bf16*)alloc(768 * 256 * sizeof(bf16));
  bf16*  wproj = (bf16*)alloc(256 * 256 * sizeof(bf16));
  bf16*  wfc1  = (bf16*)alloc(512 * 256 * sizeof(bf16));
  bf16*  wfc2  = (bf16*)alloc(256 * 512 * sizeof(bf16));
  float* qscale = (float*)alloc(768 * sizeof(float));
  float* qbias  = (float*)alloc(768 * sizeof(float));
  bf16*    xbuf = (bf16*)alloc((size_t)8192 * 256 * sizeof(bf16));
  bf16*    qb   = (bf16*)alloc((size_t)8192 * 256 * sizeof(bf16));
  uint8_t* kvf8 = (uint8_t*)alloc((size_t)8192 * 512);
  bf16*    y1   = (bf16*)alloc((size_t)8192 * 512 * sizeof(bf16));
  bf16*  attnb = (bf16*)alloc((size_t)8192 * 256 * sizeof(bf16));
  float* feat2 = (float*)alloc((size_t)8192 * 256 * sizeof(float));
  float* posm  = (float*)alloc((size_t)8192 * 48 * 8 * sizeof(float));
  float* outf = (float*)d_out;

  prep_kernel<<<dim3(768), dim3(256), 0, stream>>>(
      q_w, kv_w, proj_w, fc1_w, fc2_w, q_b, kv_b,
      wqkv, wproj, wfc1, wfc2, qscale, qbias);
  posm_kernel<<<dim3(1536), dim3(256), 0, stream>>>(
      pe_idx, cluster_mask, pre_table, pe_w, pe_b, posm);
  ln_kernel<<<dim3(2048), dim3(256), 0, stream>>>(feat, norm1_w, norm1_b, xbuf);
  gemm_bt<4, 256><<<dim3(128, 12), dim3(256), 0, stream>>>(
      xbuf, wqkv, 768, qscale, qbias, (const float*)nullptr, 0,
      (float*)nullptr, (bf16*)nullptr, qb, kvf8);
  attn_kernel<<<dim3(2048), dim3(256), 0, stream>>>(
      qb, kvf8, member_idx, posm, blank_k, blank_v, attnb);
  gemm_bt<2, 256><<<dim3(128, 8), dim3(256), 0, stream>>>(
      attnb, wproj, 256, (const float*)nullptr, proj_b,
      feat, 0, feat2, (bf16*)nullptr, (bf16*)nullptr, (uint8_t*)nullptr);
  ln_kernel<<<dim3(2048), dim3(256), 0, stream>>>(feat2, norm2_w, norm2_b, xbuf);
  gemm_bt<4, 256><<<dim3(128, 8), dim3(256), 0, stream>>>(
      xbuf, wfc1, 512, (const float*)nullptr, fc1_b,
      (const float*)nullptr, 1, (float*)nullptr, y1, (bf16*)nullptr, (uint8_t*)nullptr);
  gemm_bt<2, 512><<<dim3(128, 8), dim3(256), 0, stream>>>(
      y1, wfc2, 256, (const float*)nullptr, fc2_b,
      feat2, 0, outf, (bf16*)nullptr, (bf16*)nullptr, (uint8_t*)nullptr);
}